// Round 2
// baseline (574.351 us; speedup 1.0000x reference)
//
#include <hip/hip_runtime.h>
#include <math.h>
#include <string.h>

#define Nn 4000
#define Dd 256
#define Tt 52
#define Kk 20
#define Pp 100

// ws layout (float offsets)
#define OFF_KINV_LAM 0
#define OFF_KINV_PHI 2704
#define OFF_M_LAM    5408
#define OFF_M_PHI    8112
#define OFF_DL       10816
#define OFF_PHIP     10820                     // [t][k][d] : 52*20*256 = 266240 floats
#define OFF_THETA    277060                    // [t][n][k] : 52*4000*20 = 4160000 floats

// ---------------- device kernels ----------------

// theta_t[t][n][k] = softmax_k(lambda[n][k][t]); one thread per (n,t), t fastest
__global__ __launch_bounds__(256) void theta_kernel(const float* __restrict__ lam,
                                                    float* __restrict__ theta_t) {
    int gid = blockIdx.x * 256 + threadIdx.x;
    if (gid >= Nn * Tt) return;
    int n = gid / Tt, t = gid - n * Tt;
    const float* base = lam + n * Kk * Tt + t;
    float v[Kk];
    float m = -1e30f;
#pragma unroll
    for (int k = 0; k < Kk; ++k) { v[k] = base[k * Tt]; m = fmaxf(m, v[k]); }
    float s = 0.f;
#pragma unroll
    for (int k = 0; k < Kk; ++k) { v[k] = __expf(v[k] - m); s += v[k]; }
    float inv = 1.f / s;
    float* o = theta_t + ((size_t)t * Nn + n) * Kk;
#pragma unroll
    for (int k = 0; k < Kk; ++k) o[k] = v[k] * inv;
}

// phip_t[t][k][d] = sigmoid(phi[k][d][t]); one thread per (d,t), t fastest
__global__ __launch_bounds__(256) void phip_kernel(const float* __restrict__ phi,
                                                   float* __restrict__ phip_t) {
    int gid = blockIdx.x * 256 + threadIdx.x;   // = d*52 + t
    int d = gid / Tt, t = gid - d * Tt;
    float v[Kk];
#pragma unroll
    for (int k = 0; k < Kk; ++k) {
        float x = phi[k * (Dd * Tt) + gid];     // coalesced: lanes consecutive in t
        v[k] = 1.f / (1.f + __expf(-x));
    }
#pragma unroll
    for (int k = 0; k < Kk; ++k)
        phip_t[((size_t)t * Kk + k) * Dd + d] = v[k];
}

#define GR_ROWS 128

// M_phi += tile-Gram of (phi - logit_prev) rows; rows R = k*256+d
__global__ __launch_bounds__(256) void gram_phi_kernel(const float* __restrict__ phi,
                                                       const float* __restrict__ logit_prev,
                                                       float* __restrict__ M) {
    __shared__ float rows[GR_ROWS][56];
    int R0 = blockIdx.x * GR_ROWS;
    for (int idx = threadIdx.x; idx < GR_ROWS * Tt; idx += 256) {
        int r = idx / Tt, t = idx - r * Tt;
        int R = R0 + r;
        rows[r][t] = phi[R * Tt + t] - logit_prev[(R & 255) * Tt + t];
    }
    __syncthreads();
    int ta = threadIdx.x % 13, tb = threadIdx.x / 13;
    if (tb < 13) {
        float acc[4][4] = {};
        for (int r = 0; r < GR_ROWS; ++r) {
            float4 a = *(const float4*)&rows[r][4 * ta];
            float4 b = *(const float4*)&rows[r][4 * tb];
            float av[4] = {a.x, a.y, a.z, a.w};
            float bv[4] = {b.x, b.y, b.z, b.w};
#pragma unroll
            for (int i = 0; i < 4; ++i)
#pragma unroll
                for (int j = 0; j < 4; ++j) acc[i][j] += av[i] * bv[j];
        }
#pragma unroll
        for (int i = 0; i < 4; ++i)
#pragma unroll
            for (int j = 0; j < 4; ++j)
                atomicAdd(&M[(4 * ta + i) * Tt + 4 * tb + j], acc[i][j]);
    }
}

// M_lam += tile-Gram of (lambda - G@gamma) rows; rows R = n*20+k
__global__ __launch_bounds__(256) void gram_lam_kernel(const float* __restrict__ lam,
                                                       const float* __restrict__ G,
                                                       const float* __restrict__ gamma,
                                                       float* __restrict__ M) {
    __shared__ float rows[GR_ROWS][56];
    __shared__ float meanv[GR_ROWS];
    int R0 = blockIdx.x * GR_ROWS;
    if (threadIdx.x < GR_ROWS) {
        int R = R0 + threadIdx.x;
        int n = R / Kk, k = R - n * Kk;
        float m = 0.f;
        for (int p = 0; p < Pp; ++p) m += G[n * Pp + p] * gamma[p * Kk + k];
        meanv[threadIdx.x] = m;
    }
    __syncthreads();
    for (int idx = threadIdx.x; idx < GR_ROWS * Tt; idx += 256) {
        int r = idx / Tt, t = idx - r * Tt;
        int R = R0 + r;
        rows[r][t] = lam[R * Tt + t] - meanv[r];
    }
    __syncthreads();
    int ta = threadIdx.x % 13, tb = threadIdx.x / 13;
    if (tb < 13) {
        float acc[4][4] = {};
        for (int r = 0; r < GR_ROWS; ++r) {
            float4 a = *(const float4*)&rows[r][4 * ta];
            float4 b = *(const float4*)&rows[r][4 * tb];
            float av[4] = {a.x, a.y, a.z, a.w};
            float bv[4] = {b.x, b.y, b.z, b.w};
#pragma unroll
            for (int i = 0; i < 4; ++i)
#pragma unroll
                for (int j = 0; j < 4; ++j) acc[i][j] += av[i] * bv[j];
        }
#pragma unroll
        for (int i = 0; i < 4; ++i)
#pragma unroll
            for (int j = 0; j < 4; ++j)
                atomicAdd(&M[(4 * ta + i) * Tt + 4 * tb + j], acc[i][j]);
    }
}

// ---- device Cholesky-inverse of float32(K + jitter*I), double internals ----
// A,L,Yc are LDS arrays [52*53] (padded rows). All 256 threads participate in syncs.
__device__ void kinv_block(float ls, double jit, float* __restrict__ out,
                           double* A, double* L, double* Yc) {
    const int tid = threadIdx.x;
    float ls2 = ls * ls;
    for (int idx = tid; idx < 52 * 52; idx += 256) {
        int i = idx / 52, j = idx - 52 * i;
        int di = i - j;
        float sq = (float)(di * di);
        float arg = (-0.5f * sq) / ls2;                 // matches np float32 arithmetic
        float kf = (float)exp((double)arg);             // ~np.exp(float32) to 1 ulp
        float aij = (i == j) ? (float)(1.0 + jit) : kf; // float32(Kmat + jitter*eye)
        A[i * 53 + j] = (double)aij;
    }
    __syncthreads();
    for (int j = 0; j < 52; ++j) {
        if (tid == 0) {
            double s = A[j * 53 + j];
            for (int k = 0; k < j; ++k) { double v = L[j * 53 + k]; s -= v * v; }
            L[j * 53 + j] = sqrt(s);
        }
        __syncthreads();
        for (int i = j + 1 + tid; i < 52; i += 256) {
            double s = A[i * 53 + j];
            for (int k = 0; k < j; ++k) s -= L[i * 53 + k] * L[j * 53 + k];
            L[i * 53 + j] = s / L[j * 53 + j];
        }
        __syncthreads();
    }
    if (tid < 52) {
        int c = tid;
        for (int i = 0; i < 52; ++i) {                  // forward solve L y = e_c
            double s = (i == c) ? 1.0 : 0.0;
            for (int k = 0; k < i; ++k) s -= L[i * 53 + k] * Yc[k * 53 + c];
            Yc[i * 53 + c] = s / L[i * 53 + i];
        }
        for (int i = 51; i >= 0; --i) {                 // back solve L^T x = y
            double s = Yc[i * 53 + c];
            for (int k = i + 1; k < 52; ++k) s -= L[k * 53 + i] * Yc[k * 53 + c];
            Yc[i * 53 + c] = s / L[i * 53 + i];
        }
        for (int i = 0; i < 52; ++i) out[i * 52 + c] = (float)Yc[i * 53 + c];
    }
}

// blocks 0..499: data loss (8 n's x 256 d-lanes). blocks 500,501: K^-1 builds.
__global__ __launch_bounds__(256) void data_kinv_kernel(
    const float* __restrict__ theta_t, const float* __restrict__ phip_t,
    const float* __restrict__ Y, const int* __restrict__ ev,
    float* __restrict__ DL, float* __restrict__ kinv,
    float ls1, double j1, float ls2, double j2) {
    __shared__ double shA[52 * 53];
    __shared__ double shL[52 * 53];
    __shared__ double shY[52 * 53];
    __shared__ float wsum[4];

    if (blockIdx.x >= Nn / 8) {
        if (blockIdx.x == Nn / 8) kinv_block(ls1, j1, kinv, shA, shL, shY);
        else                      kinv_block(ls2, j2, kinv + 2704, shA, shL, shY);
        return;
    }

    const int d = threadIdx.x;
    const int n0 = blockIdx.x * 8;
    int e[8];
    float Yv[8], acc[8], pie[8];
#pragma unroll
    for (int g = 0; g < 8; ++g) {
        int n = n0 + g;
        e[g] = ev[n * Dd + d];
        Yv[g] = Y[((size_t)(n * Dd + d)) * Tt + e[g]];
        acc[g] = 0.f;
        pie[g] = 0.5f;
    }
    for (int t = 0; t < Tt; ++t) {
        float pv[Kk];
        const float* pt = phip_t + (size_t)t * (Kk * Dd) + d;
#pragma unroll
        for (int k = 0; k < Kk; ++k) pv[k] = pt[k * Dd];   // coalesced in d
        const float4* th = (const float4*)(theta_t + ((size_t)t * Nn + n0) * Kk);
#pragma unroll
        for (int g = 0; g < 8; ++g) {
            float4 a0 = th[g * 5 + 0], a1 = th[g * 5 + 1], a2 = th[g * 5 + 2],
                   a3 = th[g * 5 + 3], a4 = th[g * 5 + 4];
            float pi = a0.x * pv[0] + a0.y * pv[1] + a0.z * pv[2] + a0.w * pv[3]
                     + a1.x * pv[4] + a1.y * pv[5] + a1.z * pv[6] + a1.w * pv[7]
                     + a2.x * pv[8] + a2.y * pv[9] + a2.z * pv[10] + a2.w * pv[11]
                     + a3.x * pv[12] + a3.y * pv[13] + a3.z * pv[14] + a3.w * pv[15]
                     + a4.x * pv[16] + a4.y * pv[17] + a4.z * pv[18] + a4.w * pv[19];
            pi = fminf(fmaxf(pi, 1e-8f), 1.0f - 1e-8f);
            float lg = __logf(1.f - pi);
            if (t <= e[g]) acc[g] += lg;
            pie[g] = (t == e[g]) ? pi : pie[g];
        }
    }
    float tsum = 0.f;
#pragma unroll
    for (int g = 0; g < 8; ++g)
        tsum += acc[g] + Yv[g] * (__logf(pie[g]) - __logf(1.f - pie[g]));
    for (int off = 32; off; off >>= 1) tsum += __shfl_down(tsum, off, 64);
    if ((threadIdx.x & 63) == 0) wsum[threadIdx.x >> 6] = tsum;
    __syncthreads();
    if (threadIdx.x == 0) atomicAdd(DL, -(wsum[0] + wsum[1] + wsum[2] + wsum[3]));
}

// out = DL/N + 0.5*<Kinv_lam,M_lam>/N + 0.5*<Kinv_phi,M_phi>/D
__global__ __launch_bounds__(256) void final_kernel(const float* __restrict__ ws,
                                                    float* __restrict__ out) {
    double s = 0.0;
    for (int i = threadIdx.x; i < 2704; i += 256)
        s += (double)ws[OFF_KINV_LAM + i] * (double)ws[OFF_M_LAM + i] * (0.5 / Nn);
    for (int i = threadIdx.x; i < 2704; i += 256)
        s += (double)ws[OFF_KINV_PHI + i] * (double)ws[OFF_M_PHI + i] * (0.5 / Dd);
    __shared__ double red[256];
    red[threadIdx.x] = s;
    __syncthreads();
    for (int off = 128; off; off >>= 1) {
        if (threadIdx.x < off) red[threadIdx.x] += red[threadIdx.x + off];
        __syncthreads();
    }
    if (threadIdx.x == 0) out[0] = (float)(red[0] + (double)ws[OFF_DL] / Nn);
}

// ------------- host-side jitter search (runs ONCE at .so load, pure CPU) -------------

static void build_K_f(double ls_in, float Kf[52][52]) {
    float ls = (float)ls_in;
    float ls2 = ls * ls;
    for (int i = 0; i < 52; ++i)
        for (int j = 0; j < 52; ++j) {
            float sq = (float)((i - j) * (i - j));
            float arg = (-0.5f * sq) / ls2;
            Kf[i][j] = expf(arg);
        }
}

static void jacobi_eig(double a[52][52], double ev[52]) {
    const int n = 52;
    for (int sweep = 0; sweep < 100; ++sweep) {
        double off = 0;
        for (int p = 0; p < n - 1; ++p)
            for (int q = p + 1; q < n; ++q) off += a[p][q] * a[p][q];
        if (off < 1e-24) break;
        for (int p = 0; p < n - 1; ++p)
            for (int q = p + 1; q < n; ++q) {
                double apq = a[p][q];
                if (fabs(apq) < 1e-300) continue;
                double th = (a[q][q] - a[p][p]) / (2.0 * apq);
                double t = (th >= 0 ? 1.0 : -1.0) / (fabs(th) + sqrt(th * th + 1.0));
                double c = 1.0 / sqrt(t * t + 1.0), s = t * c;
                for (int i = 0; i < n; ++i) {
                    double aip = a[i][p], aiq = a[i][q];
                    a[i][p] = c * aip - s * aiq;
                    a[i][q] = s * aip + c * aiq;
                }
                for (int i = 0; i < n; ++i) {
                    double api = a[p][i], aqi = a[q][i];
                    a[p][i] = c * api - s * aqi;
                    a[q][i] = s * api + c * aqi;
                }
            }
    }
    for (int i = 0; i < n; ++i) ev[i] = a[i][i];
}

static double cond_of(const float Kf[52][52], double jitter) {
    double A[52][52], ev[52];
    for (int i = 0; i < 52; ++i)
        for (int j = 0; j < 52; ++j) A[i][j] = (double)Kf[i][j];
    for (int i = 0; i < 52; ++i) A[i][i] = (double)Kf[i][i] + jitter;
    jacobi_eig(A, ev);
    double mx = 0.0, mn = 1e300;
    for (int i = 0; i < 52; ++i) {
        double a = fabs(ev[i]);
        if (a > mx) mx = a;
        if (a < mn) mn = a;
    }
    if (mn <= 0.0) return 1e300;
    return mx / mn;
}

static double find_jitter(const float Kf[52][52]) {
    double jitter = 1e-4;
    while (true) {
        if (cond_of(Kf, jitter) < 1e4) break;
        jitter *= 2.0;
        if (jitter > 0.1) break;
    }
    return jitter;
}

struct JitterInit {
    double j_lam, j_phi;
    JitterInit() {
        float Kf[52][52];
        build_K_f(52.0 / 4.0, Kf);
        j_lam = find_jitter(Kf);
        build_K_f(52.0 / 3.0, Kf);
        j_phi = find_jitter(Kf);
    }
};
static JitterInit g_jit;   // runs at dlopen; kernel_launch itself is uniform per call

// ---------------- launch ----------------

extern "C" void kernel_launch(void* const* d_in, const int* in_sizes, int n_in,
                              void* d_out, int out_size, void* d_ws, size_t ws_size,
                              hipStream_t stream) {
    (void)in_sizes; (void)n_in; (void)out_size; (void)ws_size;
    const float* lam        = (const float*)d_in[0];
    const float* phi        = (const float*)d_in[1];
    const float* gamma      = (const float*)d_in[2];
    const float* G          = (const float*)d_in[3];
    const float* Y          = (const float*)d_in[4];
    const float* logit_prev = (const float*)d_in[5];
    const int*   ev         = (const int*)d_in[6];
    float* out = (float*)d_out;
    float* ws  = (float*)d_ws;

    hipMemsetAsync(ws + OFF_M_LAM, 0, (2704 * 2 + 1) * sizeof(float), stream);

    theta_kernel<<<(Nn * Tt + 255) / 256, 256, 0, stream>>>(lam, ws + OFF_THETA);
    phip_kernel<<<(Dd * Tt) / 256, 256, 0, stream>>>(phi, ws + OFF_PHIP);
    gram_phi_kernel<<<(Kk * Dd) / GR_ROWS, 256, 0, stream>>>(phi, logit_prev, ws + OFF_M_PHI);
    gram_lam_kernel<<<(Nn * Kk) / GR_ROWS, 256, 0, stream>>>(lam, G, gamma, ws + OFF_M_LAM);
    data_kinv_kernel<<<Nn / 8 + 2, 256, 0, stream>>>(
        ws + OFF_THETA, ws + OFF_PHIP, Y, ev, ws + OFF_DL, ws + OFF_KINV_LAM,
        (float)(52.0 / 4.0), g_jit.j_lam, (float)(52.0 / 3.0), g_jit.j_phi);
    final_kernel<<<1, 256, 0, stream>>>(ws, out);
}

// Round 3
// 538.193 us; speedup vs baseline: 1.0672x; 1.0672x over previous
//
#include <hip/hip_runtime.h>
#include <math.h>
#include <string.h>

#define Nn 4000
#define Dd 256
#define Tt 52
#define Kk 20
#define Pp 100

// ws layout (float offsets)
#define OFF_W_LAM    0          // host-computed K_lam^-1 * (0.5/N), 52x52
#define OFF_W_PHI    2704       // host-computed K_phi^-1 * (0.5/D), 52x52
#define OFF_M_LAM    5408
#define OFF_M_PHI    8112
#define OFF_DL       10816
#define OFF_PHIP     10820      // [t][k][d] : 52*20*256 = 266240 floats
#define OFF_THETA    277060     // [t][n][k] : 52*4000*20 = 4160000 floats

// ---------------- device kernels ----------------

// theta_t[t][n][k] = softmax_k(lambda[n][k][t]); one thread per (n,t), t fastest
__global__ __launch_bounds__(256) void theta_kernel(const float* __restrict__ lam,
                                                    float* __restrict__ theta_t) {
    int gid = blockIdx.x * 256 + threadIdx.x;
    if (gid >= Nn * Tt) return;
    int n = gid / Tt, t = gid - n * Tt;
    const float* base = lam + n * Kk * Tt + t;
    float v[Kk];
    float m = -1e30f;
#pragma unroll
    for (int k = 0; k < Kk; ++k) { v[k] = base[k * Tt]; m = fmaxf(m, v[k]); }
    float s = 0.f;
#pragma unroll
    for (int k = 0; k < Kk; ++k) { v[k] = __expf(v[k] - m); s += v[k]; }
    float inv = 1.f / s;
    float* o = theta_t + ((size_t)t * Nn + n) * Kk;
#pragma unroll
    for (int k = 0; k < Kk; ++k) o[k] = v[k] * inv;
}

// phip_t[t][k][d] = sigmoid(phi[k][d][t]); one thread per (d,t), t fastest
__global__ __launch_bounds__(256) void phip_kernel(const float* __restrict__ phi,
                                                   float* __restrict__ phip_t) {
    int gid = blockIdx.x * 256 + threadIdx.x;   // = d*52 + t
    int d = gid / Tt, t = gid - d * Tt;
    float v[Kk];
#pragma unroll
    for (int k = 0; k < Kk; ++k) {
        float x = phi[k * (Dd * Tt) + gid];     // coalesced: lanes consecutive in t
        v[k] = 1.f / (1.f + __expf(-x));
    }
#pragma unroll
    for (int k = 0; k < Kk; ++k)
        phip_t[((size_t)t * Kk + k) * Dd + d] = v[k];
}

#define GR_ROWS 128

// M_phi += Gram of (phi - logit_prev) rows; rows R = k*256+d. TILES_PER_BLOCK
// tiles per block, accumulate in regs, ONE atomic round at the end.
__global__ __launch_bounds__(256) void gram_phi_kernel(const float* __restrict__ phi,
                                                       const float* __restrict__ logit_prev,
                                                       float* __restrict__ M) {
    __shared__ float rows[GR_ROWS][56];
    int ta = threadIdx.x % 13, tb = threadIdx.x / 13;
    float acc[4][4] = {};
    for (int it = 0; it < 2; ++it) {
        int R0 = (blockIdx.x * 2 + it) * GR_ROWS;
        __syncthreads();
        for (int idx = threadIdx.x; idx < GR_ROWS * Tt; idx += 256) {
            int r = idx / Tt, t = idx - r * Tt;
            int R = R0 + r;
            rows[r][t] = phi[R * Tt + t] - logit_prev[(R & 255) * Tt + t];
        }
        __syncthreads();
        if (tb < 13) {
            for (int r = 0; r < GR_ROWS; ++r) {
                float4 a = *(const float4*)&rows[r][4 * ta];
                float4 b = *(const float4*)&rows[r][4 * tb];
                float av[4] = {a.x, a.y, a.z, a.w};
                float bv[4] = {b.x, b.y, b.z, b.w};
#pragma unroll
                for (int i = 0; i < 4; ++i)
#pragma unroll
                    for (int j = 0; j < 4; ++j) acc[i][j] += av[i] * bv[j];
            }
        }
    }
    if (tb < 13) {
#pragma unroll
        for (int i = 0; i < 4; ++i)
#pragma unroll
            for (int j = 0; j < 4; ++j)
                atomicAdd(&M[(4 * ta + i) * Tt + 4 * tb + j], acc[i][j]);
    }
}

// M_lam += Gram of (lambda - G@gamma) rows; rows R = n*20+k; 5 tiles/block
__global__ __launch_bounds__(256) void gram_lam_kernel(const float* __restrict__ lam,
                                                       const float* __restrict__ G,
                                                       const float* __restrict__ gamma,
                                                       float* __restrict__ M) {
    __shared__ float rows[GR_ROWS][56];
    __shared__ float meanv[GR_ROWS];
    int ta = threadIdx.x % 13, tb = threadIdx.x / 13;
    float acc[4][4] = {};
    for (int it = 0; it < 5; ++it) {
        int R0 = (blockIdx.x * 5 + it) * GR_ROWS;
        __syncthreads();
        if (threadIdx.x < GR_ROWS) {
            int R = R0 + threadIdx.x;
            int n = R / Kk, k = R - n * Kk;
            float m = 0.f;
            for (int p = 0; p < Pp; ++p) m += G[n * Pp + p] * gamma[p * Kk + k];
            meanv[threadIdx.x] = m;
        }
        __syncthreads();
        for (int idx = threadIdx.x; idx < GR_ROWS * Tt; idx += 256) {
            int r = idx / Tt, t = idx - r * Tt;
            int R = R0 + r;
            rows[r][t] = lam[R * Tt + t] - meanv[r];
        }
        __syncthreads();
        if (tb < 13) {
            for (int r = 0; r < GR_ROWS; ++r) {
                float4 a = *(const float4*)&rows[r][4 * ta];
                float4 b = *(const float4*)&rows[r][4 * tb];
                float av[4] = {a.x, a.y, a.z, a.w};
                float bv[4] = {b.x, b.y, b.z, b.w};
#pragma unroll
                for (int i = 0; i < 4; ++i)
#pragma unroll
                    for (int j = 0; j < 4; ++j) acc[i][j] += av[i] * bv[j];
            }
        }
    }
    if (tb < 13) {
#pragma unroll
        for (int i = 0; i < 4; ++i)
#pragma unroll
            for (int j = 0; j < 4; ++j)
                atomicAdd(&M[(4 * ta + i) * Tt + 4 * tb + j], acc[i][j]);
    }
}

// data loss: block = 8 n's x 256 d-lanes; t outer, n inner. No big LDS ->
// occupancy VGPR-limited (~5 blocks/CU) instead of 2 blocks/CU.
__global__ __launch_bounds__(256) void data_kernel(const float* __restrict__ theta_t,
                                                   const float* __restrict__ phip_t,
                                                   const float* __restrict__ Y,
                                                   const int* __restrict__ ev,
                                                   float* __restrict__ DL) {
    __shared__ float wsum[4];
    const int d = threadIdx.x;
    const int n0 = blockIdx.x * 8;
    int e[8];
    float Yv[8], acc[8], pie[8];
#pragma unroll
    for (int g = 0; g < 8; ++g) {
        int n = n0 + g;
        e[g] = ev[n * Dd + d];
        Yv[g] = Y[((size_t)(n * Dd + d)) * Tt + e[g]];   // consumed only in epilogue
        acc[g] = 0.f;
        pie[g] = 0.5f;
    }
    for (int t = 0; t < Tt; ++t) {
        float pv[Kk];
        const float* pt = phip_t + (size_t)t * (Kk * Dd) + d;
#pragma unroll
        for (int k = 0; k < Kk; ++k) pv[k] = pt[k * Dd];   // coalesced in d, L1-hot
        const float4* th = (const float4*)(theta_t + ((size_t)t * Nn + n0) * Kk);
#pragma unroll
        for (int g = 0; g < 8; ++g) {
            float4 a0 = th[g * 5 + 0], a1 = th[g * 5 + 1], a2 = th[g * 5 + 2],
                   a3 = th[g * 5 + 3], a4 = th[g * 5 + 4];   // wave-uniform
            float pi = a0.x * pv[0] + a0.y * pv[1] + a0.z * pv[2] + a0.w * pv[3]
                     + a1.x * pv[4] + a1.y * pv[5] + a1.z * pv[6] + a1.w * pv[7]
                     + a2.x * pv[8] + a2.y * pv[9] + a2.z * pv[10] + a2.w * pv[11]
                     + a3.x * pv[12] + a3.y * pv[13] + a3.z * pv[14] + a3.w * pv[15]
                     + a4.x * pv[16] + a4.y * pv[17] + a4.z * pv[18] + a4.w * pv[19];
            pi = fminf(fmaxf(pi, 1e-8f), 1.0f - 1e-8f);
            float lg = __logf(1.f - pi);
            if (t <= e[g]) acc[g] += lg;
            pie[g] = (t == e[g]) ? pi : pie[g];
        }
    }
    float tsum = 0.f;
#pragma unroll
    for (int g = 0; g < 8; ++g)
        tsum += acc[g] + Yv[g] * (__logf(pie[g]) - __logf(1.f - pie[g]));
    for (int off = 32; off; off >>= 1) tsum += __shfl_down(tsum, off, 64);
    if ((threadIdx.x & 63) == 0) wsum[threadIdx.x >> 6] = tsum;
    __syncthreads();
    if (threadIdx.x == 0) atomicAdd(DL, -(wsum[0] + wsum[1] + wsum[2] + wsum[3]));
}

// out = DL/N + <W_lam,M_lam> + <W_phi,M_phi>   (W already scaled by 0.5/N, 0.5/D)
__global__ __launch_bounds__(256) void final_kernel(const float* __restrict__ ws,
                                                    float* __restrict__ out) {
    double s = 0.0;
    for (int i = threadIdx.x; i < 2704; i += 256)
        s += (double)ws[OFF_W_LAM + i] * (double)ws[OFF_M_LAM + i];
    for (int i = threadIdx.x; i < 2704; i += 256)
        s += (double)ws[OFF_W_PHI + i] * (double)ws[OFF_M_PHI + i];
    __shared__ double red[256];
    red[threadIdx.x] = s;
    __syncthreads();
    for (int off = 128; off; off >>= 1) {
        if (threadIdx.x < off) red[threadIdx.x] += red[threadIdx.x + off];
        __syncthreads();
    }
    if (threadIdx.x == 0) out[0] = (float)(red[0] + (double)ws[OFF_DL] / Nn);
}

// ------- host-side constant math (runs ONCE at dlopen, never inside launch) -------

static void build_K_f(double ls_in, float Kf[52][52]) {
    float ls = (float)ls_in;
    float ls2 = ls * ls;
    for (int i = 0; i < 52; ++i)
        for (int j = 0; j < 52; ++j) {
            float sq = (float)((i - j) * (i - j));
            float arg = (-0.5f * sq) / ls2;
            Kf[i][j] = expf(arg);
        }
}

static void jacobi_eig(double a[52][52], double ev[52]) {
    const int n = 52;
    for (int sweep = 0; sweep < 100; ++sweep) {
        double off = 0;
        for (int p = 0; p < n - 1; ++p)
            for (int q = p + 1; q < n; ++q) off += a[p][q] * a[p][q];
        if (off < 1e-24) break;
        for (int p = 0; p < n - 1; ++p)
            for (int q = p + 1; q < n; ++q) {
                double apq = a[p][q];
                if (fabs(apq) < 1e-300) continue;
                double th = (a[q][q] - a[p][p]) / (2.0 * apq);
                double t = (th >= 0 ? 1.0 : -1.0) / (fabs(th) + sqrt(th * th + 1.0));
                double c = 1.0 / sqrt(t * t + 1.0), s = t * c;
                for (int i = 0; i < n; ++i) {
                    double aip = a[i][p], aiq = a[i][q];
                    a[i][p] = c * aip - s * aiq;
                    a[i][q] = s * aip + c * aiq;
                }
                for (int i = 0; i < n; ++i) {
                    double api = a[p][i], aqi = a[q][i];
                    a[p][i] = c * api - s * aqi;
                    a[q][i] = s * api + c * aqi;
                }
            }
    }
    for (int i = 0; i < n; ++i) ev[i] = a[i][i];
}

static void build_A(const float Kf[52][52], double jitter, double A[52][52]) {
    float jf = (float)jitter;
    for (int i = 0; i < 52; ++i)
        for (int j = 0; j < 52; ++j) A[i][j] = (double)Kf[i][j];
    for (int i = 0; i < 52; ++i) A[i][i] = (double)(float)(Kf[i][i] + jf);
}

static double cond_of(const float Kf[52][52], double jitter) {
    double A[52][52], ev[52];
    build_A(Kf, jitter, A);
    jacobi_eig(A, ev);
    double mx = 0.0, mn = 1e300;
    for (int i = 0; i < 52; ++i) {
        double a = fabs(ev[i]);
        if (a > mx) mx = a;
        if (a < mn) mn = a;
    }
    if (mn <= 0.0) return 1e300;
    return mx / mn;
}

static double find_jitter(const float Kf[52][52]) {
    double jitter = 1e-4;
    while (true) {
        if (cond_of(Kf, jitter) < 1e4) break;
        jitter *= 2.0;
        if (jitter > 0.1) break;
    }
    return jitter;
}

static void chol_inv_scaled(const float Kf[52][52], double jitter, double scale,
                            float* out /*52*52 row-major, already scaled*/) {
    const int n = 52;
    double A[52][52], L[52][52];
    build_A(Kf, jitter, A);
    memset(L, 0, sizeof(L));
    for (int j = 0; j < n; ++j) {
        double s = A[j][j];
        for (int k = 0; k < j; ++k) s -= L[j][k] * L[j][k];
        L[j][j] = sqrt(s);
        for (int i = j + 1; i < n; ++i) {
            double v = A[i][j];
            for (int k = 0; k < j; ++k) v -= L[i][k] * L[j][k];
            L[i][j] = v / L[j][j];
        }
    }
    for (int c = 0; c < n; ++c) {
        double y[52], x[52];
        for (int i = 0; i < n; ++i) {
            double v = (i == c) ? 1.0 : 0.0;
            for (int k = 0; k < i; ++k) v -= L[i][k] * y[k];
            y[i] = v / L[i][i];
        }
        for (int i = n - 1; i >= 0; --i) {
            double v = y[i];
            for (int k = i + 1; k < n; ++k) v -= L[k][i] * x[k];
            x[i] = v / L[i][i];
        }
        for (int i = 0; i < n; ++i) out[i * 52 + c] = (float)(x[i] * scale);
    }
}

struct KinvInit {
    float w[5408];   // [0:2704) = Kinv_lam*0.5/N, [2704:5408) = Kinv_phi*0.5/D
    KinvInit() {
        float Kf[52][52];
        build_K_f(52.0 / 4.0, Kf);
        chol_inv_scaled(Kf, find_jitter(Kf), 0.5 / Nn, w);
        build_K_f(52.0 / 3.0, Kf);
        chol_inv_scaled(Kf, find_jitter(Kf), 0.5 / Dd, w + 2704);
    }
};
static KinvInit g_kinv;   // dlopen-time; kernel_launch does identical work every call

// ---------------- launch ----------------

extern "C" void kernel_launch(void* const* d_in, const int* in_sizes, int n_in,
                              void* d_out, int out_size, void* d_ws, size_t ws_size,
                              hipStream_t stream) {
    (void)in_sizes; (void)n_in; (void)out_size; (void)ws_size;
    const float* lam        = (const float*)d_in[0];
    const float* phi        = (const float*)d_in[1];
    const float* gamma      = (const float*)d_in[2];
    const float* G          = (const float*)d_in[3];
    const float* Y          = (const float*)d_in[4];
    const float* logit_prev = (const float*)d_in[5];
    const int*   ev         = (const int*)d_in[6];
    float* out = (float*)d_out;
    float* ws  = (float*)d_ws;

    hipMemcpyAsync(ws + OFF_W_LAM, g_kinv.w, 5408 * sizeof(float),
                   hipMemcpyHostToDevice, stream);
    hipMemsetAsync(ws + OFF_M_LAM, 0, (2704 * 2 + 1) * sizeof(float), stream);

    theta_kernel<<<(Nn * Tt + 255) / 256, 256, 0, stream>>>(lam, ws + OFF_THETA);
    phip_kernel<<<(Dd * Tt) / 256, 256, 0, stream>>>(phi, ws + OFF_PHIP);
    gram_phi_kernel<<<20, 256, 0, stream>>>(phi, logit_prev, ws + OFF_M_PHI);
    gram_lam_kernel<<<125, 256, 0, stream>>>(lam, G, gamma, ws + OFF_M_LAM);
    data_kernel<<<Nn / 8, 256, 0, stream>>>(ws + OFF_THETA, ws + OFF_PHIP, Y, ev, ws + OFF_DL);
    final_kernel<<<1, 256, 0, stream>>>(ws, out);
}

// Round 4
// 485.947 us; speedup vs baseline: 1.1819x; 1.1075x over previous
//
#include <hip/hip_runtime.h>
#include <math.h>
#include <string.h>

#define Nn 4000
#define Dd 256
#define Tt 52
#define Kk 20
#define Pp 100
#define CH 4          // t-chunks for data kernel
#define TC 13         // Tt / CH

// ws layout (float offsets)
#define OFF_W_LAM    0          // host K_lam^-1 * (0.5/N), 52x52
#define OFF_W_PHI    2704       // host K_phi^-1 * (0.5/D), 52x52
#define OFF_M_LAM    5408
#define OFF_M_PHI    8112
#define OFF_DL       10816
#define OFF_PHIP     10820      // [t][k][d] : 52*20*256 = 266240 floats

// ---------------- device kernels ----------------

// phip_t[t][k][d] = sigmoid(phi[k][d][t]); one block per k, LDS transpose:
// coalesced(line-dense) reads AND coalesced stores.
__global__ __launch_bounds__(256) void phip_kernel(const float* __restrict__ phi,
                                                   float* __restrict__ phip_t) {
    __shared__ float sb[256][Tt + 1];
    const int k = blockIdx.x, d = threadIdx.x;
    const float4* src = (const float4*)(phi + ((size_t)k * Dd + d) * Tt);
#pragma unroll
    for (int j = 0; j < Tt / 4; ++j) {
        float4 x = src[j];
        sb[d][4 * j + 0] = 1.f / (1.f + __expf(-x.x));
        sb[d][4 * j + 1] = 1.f / (1.f + __expf(-x.y));
        sb[d][4 * j + 2] = 1.f / (1.f + __expf(-x.z));
        sb[d][4 * j + 3] = 1.f / (1.f + __expf(-x.w));
    }
    __syncthreads();
#pragma unroll 4
    for (int t = 0; t < Tt; ++t)
        phip_t[((size_t)t * Kk + k) * Dd + d] = sb[d][t];   // lanes consecutive in d
}

#define GR_ROWS 128

// M_phi += Gram of (phi - logit_prev) rows; rows R = k*256+d; 2 tiles/block
__global__ __launch_bounds__(256) void gram_phi_kernel(const float* __restrict__ phi,
                                                       const float* __restrict__ logit_prev,
                                                       float* __restrict__ M) {
    __shared__ float rows[GR_ROWS][56];
    int ta = threadIdx.x % 13, tb = threadIdx.x / 13;
    float acc[4][4] = {};
    for (int it = 0; it < 2; ++it) {
        int R0 = (blockIdx.x * 2 + it) * GR_ROWS;
        __syncthreads();
        for (int idx = threadIdx.x; idx < GR_ROWS * Tt; idx += 256) {
            int r = idx / Tt, t = idx - r * Tt;
            int R = R0 + r;
            rows[r][t] = phi[R * Tt + t] - logit_prev[(R & 255) * Tt + t];
        }
        __syncthreads();
        if (tb < 13) {
            for (int r = 0; r < GR_ROWS; ++r) {
                float4 a = *(const float4*)&rows[r][4 * ta];
                float4 b = *(const float4*)&rows[r][4 * tb];
                float av[4] = {a.x, a.y, a.z, a.w};
                float bv[4] = {b.x, b.y, b.z, b.w};
#pragma unroll
                for (int i = 0; i < 4; ++i)
#pragma unroll
                    for (int j = 0; j < 4; ++j) acc[i][j] += av[i] * bv[j];
            }
        }
    }
    if (tb < 13) {
#pragma unroll
        for (int i = 0; i < 4; ++i)
#pragma unroll
            for (int j = 0; j < 4; ++j)
                atomicAdd(&M[(4 * ta + i) * Tt + 4 * tb + j], acc[i][j]);
    }
}

// M_lam += Gram of (lambda - G@gamma) rows; rows R = n*20+k; 5 tiles/block
__global__ __launch_bounds__(256) void gram_lam_kernel(const float* __restrict__ lam,
                                                       const float* __restrict__ G,
                                                       const float* __restrict__ gamma,
                                                       float* __restrict__ M) {
    __shared__ float rows[GR_ROWS][56];
    __shared__ float meanv[GR_ROWS];
    int ta = threadIdx.x % 13, tb = threadIdx.x / 13;
    float acc[4][4] = {};
    for (int it = 0; it < 5; ++it) {
        int R0 = (blockIdx.x * 5 + it) * GR_ROWS;
        __syncthreads();
        if (threadIdx.x < GR_ROWS) {
            int R = R0 + threadIdx.x;
            int n = R / Kk, k = R - n * Kk;
            float m = 0.f;
            for (int p = 0; p < Pp; ++p) m += G[n * Pp + p] * gamma[p * Kk + k];
            meanv[threadIdx.x] = m;
        }
        __syncthreads();
        for (int idx = threadIdx.x; idx < GR_ROWS * Tt; idx += 256) {
            int r = idx / Tt, t = idx - r * Tt;
            int R = R0 + r;
            rows[r][t] = lam[R * Tt + t] - meanv[r];
        }
        __syncthreads();
        if (tb < 13) {
            for (int r = 0; r < GR_ROWS; ++r) {
                float4 a = *(const float4*)&rows[r][4 * ta];
                float4 b = *(const float4*)&rows[r][4 * tb];
                float av[4] = {a.x, a.y, a.z, a.w};
                float bv[4] = {b.x, b.y, b.z, b.w};
#pragma unroll
                for (int i = 0; i < 4; ++i)
#pragma unroll
                    for (int j = 0; j < 4; ++j) acc[i][j] += av[i] * bv[j];
            }
        }
    }
    if (tb < 13) {
#pragma unroll
        for (int i = 0; i < 4; ++i)
#pragma unroll
            for (int j = 0; j < 4; ++j)
                atomicAdd(&M[(4 * ta + i) * Tt + 4 * tb + j], acc[i][j]);
    }
}

// data loss, fused softmax. Block = (n-group of 8) x (t-chunk of 13), 256 d-lanes.
// Grid 2000 -> ~8 waves/SIMD (was 500 -> 2 blocks/CU, latency-bound).
__global__ __launch_bounds__(256) void data_kernel(const float* __restrict__ lam,
                                                   const float* __restrict__ phip_t,
                                                   const float* __restrict__ Y,
                                                   const int* __restrict__ ev,
                                                   float* __restrict__ DL) {
    __shared__ __align__(16) float thS[TC][8][Kk];   // softmax(lambda) tile, 8.3 KB
    __shared__ float lamS[8][Kk][TC + 1];            // raw lambda tile, 4.5 KB
    __shared__ float wsum[4];
    const int tid = threadIdx.x;
    const int d = tid;
    const int ng = blockIdx.x >> 2;
    const int t0 = (blockIdx.x & 3) * TC;
    const int n0 = ng * 8;

    // Phase A: stage lambda slice [8 n][20 k][13 t] (each row read once grid-wide)
    if (tid < 8 * Kk) {
        int n = tid / Kk, k = tid - n * Kk;
        const float* src = lam + ((size_t)(n0 + n) * Kk + k) * Tt + t0;
#pragma unroll
        for (int j = 0; j < TC; ++j) lamS[n][k][j] = src[j];
    }
    __syncthreads();
    // Phase B: softmax over k for each (n, j)
    if (tid < 8 * TC) {
        int n = tid / TC, j = tid - n * TC;
        float v[Kk];
        float m = -1e30f;
#pragma unroll
        for (int k = 0; k < Kk; ++k) { v[k] = lamS[n][k][j]; m = fmaxf(m, v[k]); }
        float s = 0.f;
#pragma unroll
        for (int k = 0; k < Kk; ++k) { v[k] = __expf(v[k] - m); s += v[k]; }
        float inv = 1.f / s;
#pragma unroll
        for (int k = 0; k < Kk; ++k) thS[j][n][k] = v[k] * inv;
    }

    // overlap with phase A/B: per-(n,d) event data
    int e[8];
    float Yv[8], acc[8], pie[8];
#pragma unroll
    for (int g = 0; g < 8; ++g) {
        e[g] = ev[(n0 + g) * Dd + d];                 // coalesced
        acc[g] = 0.f;
        pie[g] = 0.5f;
        Yv[g] = 0.f;
        if (e[g] >= t0 && e[g] < t0 + TC)             // only e-owning chunk gathers Y
            Yv[g] = Y[((size_t)((n0 + g) * Dd + d)) * Tt + e[g]];
    }
    __syncthreads();

    // Phase C: main loop
    for (int j = 0; j < TC; ++j) {
        int t = t0 + j;
        float pv[Kk];
        const float* pt = phip_t + (size_t)t * (Kk * Dd) + d;
#pragma unroll
        for (int k = 0; k < Kk; ++k) pv[k] = pt[k * Dd];   // coalesced in d
#pragma unroll
        for (int g = 0; g < 8; ++g) {
            const float4* th = (const float4*)&thS[j][g][0];  // LDS broadcast
            float4 a0 = th[0], a1 = th[1], a2 = th[2], a3 = th[3], a4 = th[4];
            float pi = a0.x * pv[0] + a0.y * pv[1] + a0.z * pv[2] + a0.w * pv[3]
                     + a1.x * pv[4] + a1.y * pv[5] + a1.z * pv[6] + a1.w * pv[7]
                     + a2.x * pv[8] + a2.y * pv[9] + a2.z * pv[10] + a2.w * pv[11]
                     + a3.x * pv[12] + a3.y * pv[13] + a3.z * pv[14] + a3.w * pv[15]
                     + a4.x * pv[16] + a4.y * pv[17] + a4.z * pv[18] + a4.w * pv[19];
            pi = fminf(fmaxf(pi, 1e-8f), 1.0f - 1e-8f);
            float lg = __logf(1.f - pi);
            if (t <= e[g]) acc[g] += lg;
            pie[g] = (t == e[g]) ? pi : pie[g];
        }
    }
    float tsum = 0.f;
#pragma unroll
    for (int g = 0; g < 8; ++g)
        tsum += acc[g] + Yv[g] * (__logf(pie[g]) - __logf(1.f - pie[g]));
    for (int off = 32; off; off >>= 1) tsum += __shfl_down(tsum, off, 64);
    if ((tid & 63) == 0) wsum[tid >> 6] = tsum;
    __syncthreads();
    if (tid == 0) atomicAdd(DL, -(wsum[0] + wsum[1] + wsum[2] + wsum[3]));
}

// out = DL/N + <W_lam,M_lam> + <W_phi,M_phi>   (W pre-scaled by 0.5/N, 0.5/D)
__global__ __launch_bounds__(256) void final_kernel(const float* __restrict__ ws,
                                                    float* __restrict__ out) {
    double s = 0.0;
    for (int i = threadIdx.x; i < 2704; i += 256)
        s += (double)ws[OFF_W_LAM + i] * (double)ws[OFF_M_LAM + i];
    for (int i = threadIdx.x; i < 2704; i += 256)
        s += (double)ws[OFF_W_PHI + i] * (double)ws[OFF_M_PHI + i];
    __shared__ double red[256];
    red[threadIdx.x] = s;
    __syncthreads();
    for (int off = 128; off; off >>= 1) {
        if (threadIdx.x < off) red[threadIdx.x] += red[threadIdx.x + off];
        __syncthreads();
    }
    if (threadIdx.x == 0) out[0] = (float)(red[0] + (double)ws[OFF_DL] / Nn);
}

// ------- host-side constant math (runs ONCE at dlopen, never inside launch) -------

static void build_K_f(double ls_in, float Kf[52][52]) {
    float ls = (float)ls_in;
    float ls2 = ls * ls;
    for (int i = 0; i < 52; ++i)
        for (int j = 0; j < 52; ++j) {
            float sq = (float)((i - j) * (i - j));
            float arg = (-0.5f * sq) / ls2;
            Kf[i][j] = expf(arg);
        }
}

static void jacobi_eig(double a[52][52], double ev[52]) {
    const int n = 52;
    for (int sweep = 0; sweep < 100; ++sweep) {
        double off = 0;
        for (int p = 0; p < n - 1; ++p)
            for (int q = p + 1; q < n; ++q) off += a[p][q] * a[p][q];
        if (off < 1e-24) break;
        for (int p = 0; p < n - 1; ++p)
            for (int q = p + 1; q < n; ++q) {
                double apq = a[p][q];
                if (fabs(apq) < 1e-300) continue;
                double th = (a[q][q] - a[p][p]) / (2.0 * apq);
                double t = (th >= 0 ? 1.0 : -1.0) / (fabs(th) + sqrt(th * th + 1.0));
                double c = 1.0 / sqrt(t * t + 1.0), s = t * c;
                for (int i = 0; i < n; ++i) {
                    double aip = a[i][p], aiq = a[i][q];
                    a[i][p] = c * aip - s * aiq;
                    a[i][q] = s * aip + c * aiq;
                }
                for (int i = 0; i < n; ++i) {
                    double api = a[p][i], aqi = a[q][i];
                    a[p][i] = c * api - s * aqi;
                    a[q][i] = s * api + c * aqi;
                }
            }
    }
    for (int i = 0; i < n; ++i) ev[i] = a[i][i];
}

static void build_A(const float Kf[52][52], double jitter, double A[52][52]) {
    float jf = (float)jitter;
    for (int i = 0; i < 52; ++i)
        for (int j = 0; j < 52; ++j) A[i][j] = (double)Kf[i][j];
    for (int i = 0; i < 52; ++i) A[i][i] = (double)(float)(Kf[i][i] + jf);
}

static double cond_of(const float Kf[52][52], double jitter) {
    double A[52][52], ev[52];
    build_A(Kf, jitter, A);
    jacobi_eig(A, ev);
    double mx = 0.0, mn = 1e300;
    for (int i = 0; i < 52; ++i) {
        double a = fabs(ev[i]);
        if (a > mx) mx = a;
        if (a < mn) mn = a;
    }
    if (mn <= 0.0) return 1e300;
    return mx / mn;
}

static double find_jitter(const float Kf[52][52]) {
    double jitter = 1e-4;
    while (true) {
        if (cond_of(Kf, jitter) < 1e4) break;
        jitter *= 2.0;
        if (jitter > 0.1) break;
    }
    return jitter;
}

static void chol_inv_scaled(const float Kf[52][52], double jitter, double scale,
                            float* out) {
    const int n = 52;
    double A[52][52], L[52][52];
    build_A(Kf, jitter, A);
    memset(L, 0, sizeof(L));
    for (int j = 0; j < n; ++j) {
        double s = A[j][j];
        for (int k = 0; k < j; ++k) s -= L[j][k] * L[j][k];
        L[j][j] = sqrt(s);
        for (int i = j + 1; i < n; ++i) {
            double v = A[i][j];
            for (int k = 0; k < j; ++k) v -= L[i][k] * L[j][k];
            L[i][j] = v / L[j][j];
        }
    }
    for (int c = 0; c < n; ++c) {
        double y[52], x[52];
        for (int i = 0; i < n; ++i) {
            double v = (i == c) ? 1.0 : 0.0;
            for (int k = 0; k < i; ++k) v -= L[i][k] * y[k];
            y[i] = v / L[i][i];
        }
        for (int i = n - 1; i >= 0; --i) {
            double v = y[i];
            for (int k = i + 1; k < n; ++k) v -= L[k][i] * x[k];
            x[i] = v / L[i][i];
        }
        for (int i = 0; i < n; ++i) out[i * 52 + c] = (float)(x[i] * scale);
    }
}

struct KinvInit {
    float* w;   // PINNED: [0:2704) Kinv_lam*0.5/N, [2704:5408) Kinv_phi*0.5/D
    KinvInit() {
        if (hipHostMalloc((void**)&w, 5408 * sizeof(float)) != hipSuccess)
            w = (float*)malloc(5408 * sizeof(float));   // pageable fallback
        float Kf[52][52];
        build_K_f(52.0 / 4.0, Kf);
        chol_inv_scaled(Kf, find_jitter(Kf), 0.5 / Nn, w);
        build_K_f(52.0 / 3.0, Kf);
        chol_inv_scaled(Kf, find_jitter(Kf), 0.5 / Dd, w + 2704);
    }
};
static KinvInit g_kinv;   // dlopen-time; kernel_launch does identical work every call

// ---------------- launch ----------------

extern "C" void kernel_launch(void* const* d_in, const int* in_sizes, int n_in,
                              void* d_out, int out_size, void* d_ws, size_t ws_size,
                              hipStream_t stream) {
    (void)in_sizes; (void)n_in; (void)out_size; (void)ws_size;
    const float* lam        = (const float*)d_in[0];
    const float* phi        = (const float*)d_in[1];
    const float* gamma      = (const float*)d_in[2];
    const float* G          = (const float*)d_in[3];
    const float* Y          = (const float*)d_in[4];
    const float* logit_prev = (const float*)d_in[5];
    const int*   ev         = (const int*)d_in[6];
    float* out = (float*)d_out;
    float* ws  = (float*)d_ws;

    hipMemcpyAsync(ws + OFF_W_LAM, g_kinv.w, 5408 * sizeof(float),
                   hipMemcpyHostToDevice, stream);
    hipMemsetAsync(ws + OFF_M_LAM, 0, (2704 * 2 + 1) * sizeof(float), stream);

    phip_kernel<<<Kk, 256, 0, stream>>>(phi, ws + OFF_PHIP);
    gram_phi_kernel<<<20, 256, 0, stream>>>(phi, logit_prev, ws + OFF_M_PHI);
    gram_lam_kernel<<<125, 256, 0, stream>>>(lam, G, gamma, ws + OFF_M_LAM);
    data_kernel<<<(Nn / 8) * CH, 256, 0, stream>>>(lam, ws + OFF_PHIP, Y, ev, ws + OFF_DL);
    final_kernel<<<1, 256, 0, stream>>>(ws, out);
}

// Round 5
// 479.801 us; speedup vs baseline: 1.1971x; 1.0128x over previous
//
#include <hip/hip_runtime.h>
#include <math.h>
#include <string.h>

#define Nn 4000
#define Dd 256
#define Tt 52
#define Kk 20
#define Pp 100
#define CH 13         // t-chunks for data kernel
#define TC 4          // Tt / CH

// ws layout (float offsets)
#define OFF_W_LAM    0          // host K_lam^-1 * (0.5/N), 52x52
#define OFF_W_PHI    2704       // host K_phi^-1 * (0.5/D), 52x52
#define OFF_M_LAM    5408
#define OFF_M_PHI    8112
#define OFF_DL       10816
#define OFF_EVP      10820      // u8[4000*256] = 256000 floats
#define OFF_PHIP     266820     // [t][k][d] : 52*20*256 = 266240 floats
#define OFF_THETA    533060     // [t][n][k] : 52*4000*20 = 4160000 floats

#define GR_ROWS 128

// prep kernel block-role ranges
#define RB_PHIP0   0      // 52 blocks: sigmoid transpose
#define RB_THETA0  52     // 813 blocks: softmax -> theta_t
#define RB_GPHI0   865    // 20 blocks: gram of phi deviations
#define RB_GLAM0   885    // 125 blocks: gram of lambda deviations
#define RB_EV0     1010   // 128 blocks: ev int32 -> u8 pack
#define RB_TOTAL   1138

// ---------------- merged prep kernel ----------------
__global__ __launch_bounds__(256) void prep_kernel(
    const float* __restrict__ lam, const float* __restrict__ phi,
    const float* __restrict__ gamma, const float* __restrict__ G,
    const float* __restrict__ logit_prev, const int* __restrict__ ev,
    float* __restrict__ theta_t, float* __restrict__ phip_t,
    unsigned char* __restrict__ evp,
    float* __restrict__ M_lam, float* __restrict__ M_phi) {
    __shared__ float rows[GR_ROWS][56];
    __shared__ float meanv[GR_ROWS];
    const int bx = blockIdx.x, tid = threadIdx.x;

    if (bx < RB_THETA0) {
        // phip_t[t][k][d] = sigmoid(phi[k][d][t]); thread per (d,t)
        int gid = bx * 256 + tid;                    // d*52 + t
        int d = gid / Tt, t = gid - d * Tt;
        float v[Kk];
#pragma unroll
        for (int k = 0; k < Kk; ++k) {
            float x = phi[k * (Dd * Tt) + gid];      // lanes consecutive in t
            v[k] = 1.f / (1.f + __expf(-x));
        }
#pragma unroll
        for (int k = 0; k < Kk; ++k)
            phip_t[((size_t)t * Kk + k) * Dd + d] = v[k];
        return;
    }
    if (bx < RB_GPHI0) {
        // theta_t[t][n][k] = softmax_k(lambda[n][k][t]); thread per (n,t)
        int gid = (bx - RB_THETA0) * 256 + tid;
        if (gid >= Nn * Tt) return;
        int n = gid / Tt, t = gid - n * Tt;
        const float* base = lam + n * Kk * Tt + t;
        float v[Kk];
        float m = -1e30f;
#pragma unroll
        for (int k = 0; k < Kk; ++k) { v[k] = base[k * Tt]; m = fmaxf(m, v[k]); }
        float s = 0.f;
#pragma unroll
        for (int k = 0; k < Kk; ++k) { v[k] = __expf(v[k] - m); s += v[k]; }
        float inv = 1.f / s;
        float* o = theta_t + ((size_t)t * Nn + n) * Kk;
#pragma unroll
        for (int k = 0; k < Kk; ++k) o[k] = v[k] * inv;
        return;
    }
    if (bx < RB_GLAM0) {
        // M_phi += Gram of (phi - logit_prev); 2 tiles/block
        int ta = tid % 13, tb = tid / 13;
        float acc[4][4] = {};
        for (int it = 0; it < 2; ++it) {
            int R0 = ((bx - RB_GPHI0) * 2 + it) * GR_ROWS;
            __syncthreads();
            for (int idx = tid; idx < GR_ROWS * Tt; idx += 256) {
                int r = idx / Tt, t = idx - r * Tt;
                int R = R0 + r;
                rows[r][t] = phi[R * Tt + t] - logit_prev[(R & 255) * Tt + t];
            }
            __syncthreads();
            if (tb < 13) {
                for (int r = 0; r < GR_ROWS; ++r) {
                    float4 a = *(const float4*)&rows[r][4 * ta];
                    float4 b = *(const float4*)&rows[r][4 * tb];
                    float av[4] = {a.x, a.y, a.z, a.w};
                    float bv[4] = {b.x, b.y, b.z, b.w};
#pragma unroll
                    for (int i = 0; i < 4; ++i)
#pragma unroll
                        for (int j = 0; j < 4; ++j) acc[i][j] += av[i] * bv[j];
                }
            }
        }
        if (tb < 13)
#pragma unroll
            for (int i = 0; i < 4; ++i)
#pragma unroll
                for (int j = 0; j < 4; ++j)
                    atomicAdd(&M_phi[(4 * ta + i) * Tt + 4 * tb + j], acc[i][j]);
        return;
    }
    if (bx < RB_EV0) {
        // M_lam += Gram of (lambda - G@gamma); 5 tiles/block
        int ta = tid % 13, tb = tid / 13;
        float acc[4][4] = {};
        for (int it = 0; it < 5; ++it) {
            int R0 = ((bx - RB_GLAM0) * 5 + it) * GR_ROWS;
            __syncthreads();
            if (tid < GR_ROWS) {
                int R = R0 + tid;
                int n = R / Kk, k = R - n * Kk;
                float m = 0.f;
                for (int p = 0; p < Pp; ++p) m += G[n * Pp + p] * gamma[p * Kk + k];
                meanv[tid] = m;
            }
            __syncthreads();
            for (int idx = tid; idx < GR_ROWS * Tt; idx += 256) {
                int r = idx / Tt, t = idx - r * Tt;
                int R = R0 + r;
                rows[r][t] = lam[R * Tt + t] - meanv[r];
            }
            __syncthreads();
            if (tb < 13) {
                for (int r = 0; r < GR_ROWS; ++r) {
                    float4 a = *(const float4*)&rows[r][4 * ta];
                    float4 b = *(const float4*)&rows[r][4 * tb];
                    float av[4] = {a.x, a.y, a.z, a.w};
                    float bv[4] = {b.x, b.y, b.z, b.w};
#pragma unroll
                    for (int i = 0; i < 4; ++i)
#pragma unroll
                        for (int j = 0; j < 4; ++j) acc[i][j] += av[i] * bv[j];
                }
            }
        }
        if (tb < 13)
#pragma unroll
            for (int i = 0; i < 4; ++i)
#pragma unroll
                for (int j = 0; j < 4; ++j)
                    atomicAdd(&M_lam[(4 * ta + i) * Tt + 4 * tb + j], acc[i][j]);
        return;
    }
    {
        // ev int32 -> u8 pack (e < 52 < 256)
        const int4* src = (const int4*)ev;            // 256000 int4s
        unsigned int* dst = (unsigned int*)evp;
        int gtid = (bx - RB_EV0) * 256 + tid;         // 32768 threads
        for (int i = gtid; i < (Nn * Dd) / 4; i += 128 * 256) {
            int4 v = src[i];
            dst[i] = (unsigned)v.x | ((unsigned)v.y << 8) |
                     ((unsigned)v.z << 16) | ((unsigned)v.w << 24);
        }
        return;
    }
}

// ---------------- data loss kernel ----------------
// grid 6500: ng = blockIdx/13 (8 n's), chunk c = blockIdx%13 (4 t's), 256 d-lanes
__global__ __launch_bounds__(256) void data_kernel(const float* __restrict__ theta_t,
                                                   const float* __restrict__ phip_t,
                                                   const float* __restrict__ Y,
                                                   const unsigned char* __restrict__ evp,
                                                   float* __restrict__ DL) {
    __shared__ __align__(16) float thS[TC][8][Kk];   // 2.56 KB
    __shared__ float wsum[4];
    const int tid = threadIdx.x;
    const int d = tid;
    const int ng = blockIdx.x / CH;
    const int t0 = (blockIdx.x - ng * CH) * TC;
    const int n0 = ng * 8;

    // stage softmax tile: [4 t][8 n][20 k], dense 160-float runs per t
    for (int idx = tid; idx < TC * 8 * Kk; idx += 256) {
        int j = idx / 160, rem = idx - j * 160;
        thS[j][rem / Kk][rem - (rem / Kk) * Kk] =
            theta_t[((size_t)(t0 + j) * Nn + n0) * Kk + rem];
    }

    int e[8];
    float Yv[8], acc[8], pie[8];
#pragma unroll
    for (int g = 0; g < 8; ++g) {
        e[g] = evp[(n0 + g) * Dd + d];                // u8, coalesced
        acc[g] = 0.f;
        pie[g] = 0.5f;
        Yv[g] = 0.f;
        if (e[g] >= t0 && e[g] < t0 + TC)             // only e-owning chunk gathers Y
            Yv[g] = Y[((size_t)((n0 + g) * Dd + d)) * Tt + e[g]];
    }
    __syncthreads();

    // main loop: pv double-buffered (prefetch t+1 during t's FMAs)
    const float* ptbase = phip_t + d;
    float pvA[Kk], pvB[Kk];
#pragma unroll
    for (int k = 0; k < Kk; ++k)
        pvA[k] = ptbase[((size_t)t0 * Kk + k) * Dd];
#pragma unroll
    for (int j = 0; j < TC; ++j) {
        float* cur = (j & 1) ? pvB : pvA;
        float* nxt = (j & 1) ? pvA : pvB;
        if (j < TC - 1) {
#pragma unroll
            for (int k = 0; k < Kk; ++k)
                nxt[k] = ptbase[((size_t)(t0 + j + 1) * Kk + k) * Dd];
        }
        int t = t0 + j;
#pragma unroll
        for (int g = 0; g < 8; ++g) {
            const float4* th = (const float4*)&thS[j][g][0];  // LDS broadcast
            float4 a0 = th[0], a1 = th[1], a2 = th[2], a3 = th[3], a4 = th[4];
            float pi = a0.x * cur[0] + a0.y * cur[1] + a0.z * cur[2] + a0.w * cur[3]
                     + a1.x * cur[4] + a1.y * cur[5] + a1.z * cur[6] + a1.w * cur[7]
                     + a2.x * cur[8] + a2.y * cur[9] + a2.z * cur[10] + a2.w * cur[11]
                     + a3.x * cur[12] + a3.y * cur[13] + a3.z * cur[14] + a3.w * cur[15]
                     + a4.x * cur[16] + a4.y * cur[17] + a4.z * cur[18] + a4.w * cur[19];
            pi = fminf(fmaxf(pi, 1e-8f), 1.0f - 1e-8f);
            float lg = __logf(1.f - pi);
            if (t <= e[g]) acc[g] += lg;
            pie[g] = (t == e[g]) ? pi : pie[g];
        }
    }
    float tsum = 0.f;
#pragma unroll
    for (int g = 0; g < 8; ++g)
        tsum += acc[g] + Yv[g] * (__logf(pie[g]) - __logf(1.f - pie[g]));
    for (int off = 32; off; off >>= 1) tsum += __shfl_down(tsum, off, 64);
    if ((tid & 63) == 0) wsum[tid >> 6] = tsum;
    __syncthreads();
    if (tid == 0) atomicAdd(DL, -(wsum[0] + wsum[1] + wsum[2] + wsum[3]));
}

// out = DL/N + <W_lam,M_lam> + <W_phi,M_phi>   (W pre-scaled by 0.5/N, 0.5/D)
__global__ __launch_bounds__(256) void final_kernel(const float* __restrict__ ws,
                                                    float* __restrict__ out) {
    double s = 0.0;
    for (int i = threadIdx.x; i < 2704; i += 256)
        s += (double)ws[OFF_W_LAM + i] * (double)ws[OFF_M_LAM + i];
    for (int i = threadIdx.x; i < 2704; i += 256)
        s += (double)ws[OFF_W_PHI + i] * (double)ws[OFF_M_PHI + i];
    __shared__ double red[256];
    red[threadIdx.x] = s;
    __syncthreads();
    for (int off = 128; off; off >>= 1) {
        if (threadIdx.x < off) red[threadIdx.x] += red[threadIdx.x + off];
        __syncthreads();
    }
    if (threadIdx.x == 0) out[0] = (float)(red[0] + (double)ws[OFF_DL] / Nn);
}

// ------- host-side constant math (runs ONCE at dlopen, never inside launch) -------

static void build_K_f(double ls_in, float Kf[52][52]) {
    float ls = (float)ls_in;
    float ls2 = ls * ls;
    for (int i = 0; i < 52; ++i)
        for (int j = 0; j < 52; ++j) {
            float sq = (float)((i - j) * (i - j));
            float arg = (-0.5f * sq) / ls2;
            Kf[i][j] = expf(arg);
        }
}

static void jacobi_eig(double a[52][52], double ev[52]) {
    const int n = 52;
    for (int sweep = 0; sweep < 100; ++sweep) {
        double off = 0;
        for (int p = 0; p < n - 1; ++p)
            for (int q = p + 1; q < n; ++q) off += a[p][q] * a[p][q];
        if (off < 1e-24) break;
        for (int p = 0; p < n - 1; ++p)
            for (int q = p + 1; q < n; ++q) {
                double apq = a[p][q];
                if (fabs(apq) < 1e-300) continue;
                double th = (a[q][q] - a[p][p]) / (2.0 * apq);
                double t = (th >= 0 ? 1.0 : -1.0) / (fabs(th) + sqrt(th * th + 1.0));
                double c = 1.0 / sqrt(t * t + 1.0), s = t * c;
                for (int i = 0; i < n; ++i) {
                    double aip = a[i][p], aiq = a[i][q];
                    a[i][p] = c * aip - s * aiq;
                    a[i][q] = s * aip + c * aiq;
                }
                for (int i = 0; i < n; ++i) {
                    double api = a[p][i], aqi = a[q][i];
                    a[p][i] = c * api - s * aqi;
                    a[q][i] = s * api + c * aqi;
                }
            }
    }
    for (int i = 0; i < n; ++i) ev[i] = a[i][i];
}

static void build_A(const float Kf[52][52], double jitter, double A[52][52]) {
    float jf = (float)jitter;
    for (int i = 0; i < 52; ++i)
        for (int j = 0; j < 52; ++j) A[i][j] = (double)Kf[i][j];
    for (int i = 0; i < 52; ++i) A[i][i] = (double)(float)(Kf[i][i] + jf);
}

static double cond_of(const float Kf[52][52], double jitter) {
    double A[52][52], ev[52];
    build_A(Kf, jitter, A);
    jacobi_eig(A, ev);
    double mx = 0.0, mn = 1e300;
    for (int i = 0; i < 52; ++i) {
        double a = fabs(ev[i]);
        if (a > mx) mx = a;
        if (a < mn) mn = a;
    }
    if (mn <= 0.0) return 1e300;
    return mx / mn;
}

static double find_jitter(const float Kf[52][52]) {
    double jitter = 1e-4;
    while (true) {
        if (cond_of(Kf, jitter) < 1e4) break;
        jitter *= 2.0;
        if (jitter > 0.1) break;
    }
    return jitter;
}

static void chol_inv_scaled(const float Kf[52][52], double jitter, double scale,
                            float* out) {
    const int n = 52;
    double A[52][52], L[52][52];
    build_A(Kf, jitter, A);
    memset(L, 0, sizeof(L));
    for (int j = 0; j < n; ++j) {
        double s = A[j][j];
        for (int k = 0; k < j; ++k) s -= L[j][k] * L[j][k];
        L[j][j] = sqrt(s);
        for (int i = j + 1; i < n; ++i) {
            double v = A[i][j];
            for (int k = 0; k < j; ++k) v -= L[i][k] * L[j][k];
            L[i][j] = v / L[j][j];
        }
    }
    for (int c = 0; c < n; ++c) {
        double y[52], x[52];
        for (int i = 0; i < n; ++i) {
            double v = (i == c) ? 1.0 : 0.0;
            for (int k = 0; k < i; ++k) v -= L[i][k] * y[k];
            y[i] = v / L[i][i];
        }
        for (int i = n - 1; i >= 0; --i) {
            double v = y[i];
            for (int k = i + 1; k < n; ++k) v -= L[k][i] * x[k];
            x[i] = v / L[i][i];
        }
        for (int i = 0; i < n; ++i) out[i * 52 + c] = (float)(x[i] * scale);
    }
}

struct KinvInit {
    float* w;   // PINNED: [0:2704) Kinv_lam*0.5/N, [2704:5408) Kinv_phi*0.5/D
    KinvInit() {
        if (hipHostMalloc((void**)&w, 5408 * sizeof(float)) != hipSuccess)
            w = (float*)malloc(5408 * sizeof(float));
        float Kf[52][52];
        build_K_f(52.0 / 4.0, Kf);
        chol_inv_scaled(Kf, find_jitter(Kf), 0.5 / Nn, w);
        build_K_f(52.0 / 3.0, Kf);
        chol_inv_scaled(Kf, find_jitter(Kf), 0.5 / Dd, w + 2704);
    }
};
static KinvInit g_kinv;   // dlopen-time; kernel_launch does identical work every call

// ---------------- launch ----------------

extern "C" void kernel_launch(void* const* d_in, const int* in_sizes, int n_in,
                              void* d_out, int out_size, void* d_ws, size_t ws_size,
                              hipStream_t stream) {
    (void)in_sizes; (void)n_in; (void)out_size; (void)ws_size;
    const float* lam        = (const float*)d_in[0];
    const float* phi        = (const float*)d_in[1];
    const float* gamma      = (const float*)d_in[2];
    const float* G          = (const float*)d_in[3];
    const float* Y          = (const float*)d_in[4];
    const float* logit_prev = (const float*)d_in[5];
    const int*   ev         = (const int*)d_in[6];
    float* out = (float*)d_out;
    float* ws  = (float*)d_ws;

    hipMemcpyAsync(ws + OFF_W_LAM, g_kinv.w, 5408 * sizeof(float),
                   hipMemcpyHostToDevice, stream);
    hipMemsetAsync(ws + OFF_M_LAM, 0, (2704 * 2 + 1) * sizeof(float), stream);

    prep_kernel<<<RB_TOTAL, 256, 0, stream>>>(
        lam, phi, gamma, G, logit_prev, ev,
        ws + OFF_THETA, ws + OFF_PHIP, (unsigned char*)(ws + OFF_EVP),
        ws + OFF_M_LAM, ws + OFF_M_PHI);
    data_kernel<<<(Nn / 8) * CH, 256, 0, stream>>>(
        ws + OFF_THETA, ws + OFF_PHIP, Y, (const unsigned char*)(ws + OFF_EVP),
        ws + OFF_DL);
    final_kernel<<<1, 256, 0, stream>>>(ws, out);
}